// Round 1
// baseline (7257.942 us; speedup 1.0000x reference)
//
#include <hip/hip_runtime.h>

#define THREADS 256

// ---------------- degree / norm precompute ----------------

__global__ void deg_kernel(const int* __restrict__ col, float* __restrict__ deg, int nE) {
    int stride = gridDim.x * blockDim.x;
    for (int e = blockIdx.x * blockDim.x + threadIdx.x; e < nE; e += stride)
        atomicAdd(&deg[col[e]], 1.0f);
}

__global__ void dinv_kernel(float* __restrict__ deg, int n) {
    int i = blockIdx.x * blockDim.x + threadIdx.x;
    if (i < n) {
        float d = deg[i];
        deg[i] = d > 0.f ? rsqrtf(fmaxf(d, 1.f)) : 0.f;
    }
}

__global__ void norm_kernel(const float* __restrict__ dinv, const int* __restrict__ row,
                            const int* __restrict__ col, float* __restrict__ norm, int nE) {
    int stride = gridDim.x * blockDim.x;
    for (int e = blockIdx.x * blockDim.x + threadIdx.x; e < nE; e += stride)
        norm[e] = dinv[row[e]] * dinv[col[e]];
}

// ---------------- GEMM: X[nrows,128] @ W[128,DOUT] -> Y[nrows,DOUT] ----------------
// W staged fully in LDS ([k][col] layout: lanes read consecutive cols -> conflict-free).
// X rows staged in LDS, read as wave-uniform broadcasts. Each thread accumulates
// RPT rows for one col, amortizing the W read.

template <int DOUT, int ROWS>
__launch_bounds__(256)
__global__ void gemm_kernel(const float* __restrict__ X, const float* __restrict__ W,
                            float* __restrict__ Y, int nrows) {
    __shared__ float Ws[128 * DOUT];
    __shared__ float Xs[ROWS][132];
    const int tid = threadIdx.x;
    for (int i = tid; i < 128 * DOUT; i += 256) Ws[i] = W[i];

    const int col = tid % DOUT;
    const int rb  = tid / DOUT;
    constexpr int RPI = 256 / DOUT;   // rows computed per k-loop pass
    constexpr int RPT = ROWS / RPI;   // rows per thread

    const int nchunks = (nrows + ROWS - 1) / ROWS;
    for (int chunk = blockIdx.x; chunk < nchunks; chunk += gridDim.x) {
        const int r0 = chunk * ROWS;
        const int nr = min(ROWS, nrows - r0);
        __syncthreads();   // protect Xs from previous iteration's readers (also covers Ws on iter 0)
        for (int i = tid; i < nr * 128; i += 256) {
            int r = i >> 7, k = i & 127;
            Xs[r][k] = X[(size_t)(r0 + r) * 128 + k];
        }
        __syncthreads();
        float acc[RPT];
#pragma unroll
        for (int i = 0; i < RPT; ++i) acc[i] = 0.f;
#pragma unroll 4
        for (int k = 0; k < 128; ++k) {
            float w = Ws[k * DOUT + col];
#pragma unroll
            for (int i = 0; i < RPT; ++i)
                acc[i] += Xs[rb + i * RPI][k] * w;
        }
#pragma unroll
        for (int i = 0; i < RPT; ++i) {
            int r = rb + i * RPI;
            if (r < nr) Y[(size_t)(r0 + r) * DOUT + col] = acc[i];
        }
    }
}

// ---------------- edge scatter: out[col] += norm * xw[row] ----------------
// One thread per (edge, 4-feature group). Gather is float4-coalesced within the
// 16/32-lane group sharing an edge; scatter is 4 global f32 atomics.

template <int D>
__launch_bounds__(256)
__global__ void scatter_kernel(const float4* __restrict__ XW, const int* __restrict__ row,
                               const int* __restrict__ col, const float* __restrict__ norm,
                               float* __restrict__ out, int nE) {
    constexpr int G = D / 4;
    constexpr int LOG2G = (G == 32) ? 5 : 4;
    size_t total  = (size_t)nE * G;
    size_t stride = (size_t)gridDim.x * blockDim.x;
    for (size_t w = blockIdx.x * (size_t)blockDim.x + threadIdx.x; w < total; w += stride) {
        int e = (int)(w >> LOG2G);
        int g = (int)(w & (G - 1));
        float nv = norm[e];
        float4 x = XW[((size_t)row[e] << LOG2G) + g];
        float* o = out + (size_t)col[e] * D + g * 4;
        atomicAdd(o + 0, nv * x.x);
        atomicAdd(o + 1, nv * x.y);
        atomicAdd(o + 2, nv * x.z);
        atomicAdd(o + 3, nv * x.w);
    }
}

// ---------------- bias + relu (in place) ----------------

template <int D>
__launch_bounds__(256)
__global__ void bias_relu_kernel(float* __restrict__ Y, const float* __restrict__ b, size_t total) {
    size_t stride = (size_t)gridDim.x * blockDim.x;
    for (size_t i = blockIdx.x * (size_t)blockDim.x + threadIdx.x; i < total; i += stride) {
        float v = Y[i] + b[i & (D - 1)];
        Y[i] = v > 0.f ? v : 0.f;
    }
}

extern "C" void kernel_launch(void* const* d_in, const int* in_sizes, int n_in,
                              void* d_out, int out_size, void* d_ws, size_t ws_size,
                              hipStream_t stream) {
    const float* feats = (const float*)d_in[0];
    const int*   ei    = (const int*)d_in[1];
    const float* W1    = (const float*)d_in[2];
    const float* b1    = (const float*)d_in[3];
    const float* W2    = (const float*)d_in[4];
    const float* b2    = (const float*)d_in[5];
    const float* W3    = (const float*)d_in[6];
    const float* b3    = (const float*)d_in[7];
    float* out = (float*)d_out;

    const int N = in_sizes[0] / 128;
    const int E = in_sizes[1] / 2;
    const int* row = ei;       // source
    const int* col = ei + E;   // destination

    // workspace layout (floats): dinv[N] | norm[E] | bufA[N*128] | bufB[N*128]
    float* ws   = (float*)d_ws;
    float* dinv = ws;
    float* norm = dinv + (((size_t)N + 63) & ~(size_t)63);
    float* bufA = norm + (((size_t)E + 63) & ~(size_t)63);
    float* bufB = bufA + (size_t)N * 128;

    // degree -> dinv -> per-edge norm
    hipMemsetAsync(dinv, 0, (size_t)N * sizeof(float), stream);
    deg_kernel<<<2048, THREADS, 0, stream>>>(col, dinv, E);
    dinv_kernel<<<(N + THREADS - 1) / THREADS, THREADS, 0, stream>>>(dinv, N);
    norm_kernel<<<2048, THREADS, 0, stream>>>(dinv, row, col, norm, E);

    // ---- layer 1: feats @ W1 -> bufA; agg -> bufB; +b1, relu ----
    gemm_kernel<128, 8><<<1024, 256, 0, stream>>>(feats, W1, bufA, N);
    hipMemsetAsync(bufB, 0, (size_t)N * 128 * sizeof(float), stream);
    scatter_kernel<128><<<8192, 256, 0, stream>>>((const float4*)bufA, row, col, norm, bufB, E);
    bias_relu_kernel<128><<<4096, 256, 0, stream>>>(bufB, b1, (size_t)N * 128);

    // ---- layer 2: bufB @ W2 -> bufA; agg -> bufB; +b2, relu ----
    gemm_kernel<128, 8><<<1024, 256, 0, stream>>>(bufB, W2, bufA, N);
    hipMemsetAsync(bufB, 0, (size_t)N * 128 * sizeof(float), stream);  // stream-ordered after gemm read
    scatter_kernel<128><<<8192, 256, 0, stream>>>((const float4*)bufA, row, col, norm, bufB, E);
    bias_relu_kernel<128><<<4096, 256, 0, stream>>>(bufB, b2, (size_t)N * 128);

    // ---- layer 3: bufB @ W3 -> bufA (N x 64); agg -> d_out; +b3, relu ----
    gemm_kernel<64, 8><<<1024, 256, 0, stream>>>(bufB, W3, bufA, N);
    hipMemsetAsync(out, 0, (size_t)N * 64 * sizeof(float), stream);
    scatter_kernel<64><<<8192, 256, 0, stream>>>((const float4*)bufA, row, col, norm, out, E);
    bias_relu_kernel<64><<<4096, 256, 0, stream>>>(out, b3, (size_t)N * 64);
}

// Round 2
// 877.592 us; speedup vs baseline: 8.2703x; 8.2703x over previous
//
#include <hip/hip_runtime.h>

#define THREADS 256
#define ALIGNUP(x) (((x) + 255) & ~(size_t)255)

// ---------------- degree histogram (int) ----------------

__global__ void deg_kernel(const int* __restrict__ col, int* __restrict__ deg, int nE) {
    int stride = gridDim.x * blockDim.x;
    for (int e = blockIdx.x * blockDim.x + threadIdx.x; e < nE; e += stride)
        atomicAdd(&deg[col[e]], 1);
}

__global__ void dinv_kernel(const int* __restrict__ deg, float* __restrict__ dinv, int n) {
    int i = blockIdx.x * blockDim.x + threadIdx.x;
    if (i < n) {
        float d = (float)deg[i];
        dinv[i] = d > 0.f ? rsqrtf(fmaxf(d, 1.f)) : 0.f;
    }
}

// ---------------- exclusive scan over deg -> off (3-phase) ----------------

__global__ void scan1_kernel(const int* __restrict__ deg, int* __restrict__ off,
                             int* __restrict__ partials, int n) {
    __shared__ int s[256];
    int tid = threadIdx.x;
    int gid = blockIdx.x * 256 + tid;
    int v = gid < n ? deg[gid] : 0;
    s[tid] = v;
    __syncthreads();
    for (int o = 1; o < 256; o <<= 1) {
        int t = (tid >= o) ? s[tid - o] : 0;
        __syncthreads();
        s[tid] += t;
        __syncthreads();
    }
    if (gid < n) off[gid] = s[tid] - v;          // exclusive within block
    if (tid == 255) partials[blockIdx.x] = s[255];
}

__global__ void scan2_kernel(int* __restrict__ partials, int nblk) {
    __shared__ int s[1024];
    int tid = threadIdx.x;
    int v = tid < nblk ? partials[tid] : 0;
    s[tid] = v;
    __syncthreads();
    for (int o = 1; o < 1024; o <<= 1) {
        int t = (tid >= o) ? s[tid - o] : 0;
        __syncthreads();
        s[tid] += t;
        __syncthreads();
    }
    if (tid < nblk) partials[tid] = s[tid] - v;  // exclusive block bases
}

__global__ void scan3_kernel(int* __restrict__ off, int* __restrict__ cursor,
                             const int* __restrict__ partials, int n, int nE) {
    int gid = blockIdx.x * 256 + threadIdx.x;
    if (gid < n) {
        int o = off[gid] + partials[blockIdx.x];
        off[gid] = o;
        cursor[gid] = o;
    }
    if (gid == 0) off[n] = nE;
}

// ---------------- fill CSR: srcs sorted by destination ----------------

__global__ void fill_kernel(const int* __restrict__ row, const int* __restrict__ col,
                            int* __restrict__ cursor, int* __restrict__ srcs, int nE) {
    int stride = gridDim.x * blockDim.x;
    for (int e = blockIdx.x * blockDim.x + threadIdx.x; e < nE; e += stride) {
        int pos = atomicAdd(&cursor[col[e]], 1);
        srcs[pos] = row[e];
    }
}

// ---------------- GEMM: Y[r] = dinv[r] * (X[r] @ W), X 128-wide ----------------

template <int DOUT, int ROWS>
__launch_bounds__(256)
__global__ void gemm_kernel(const float* __restrict__ X, const float* __restrict__ W,
                            const float* __restrict__ dinv, float* __restrict__ Y, int nrows) {
    __shared__ float Ws[128 * DOUT];
    __shared__ float Xs[ROWS][132];
    const int tid = threadIdx.x;
    for (int i = tid; i < 128 * DOUT; i += 256) Ws[i] = W[i];

    const int col = tid % DOUT;
    const int rb  = tid / DOUT;
    constexpr int RPI = 256 / DOUT;   // rows computed per k-loop pass
    constexpr int RPT = ROWS / RPI;   // rows per thread

    const int nchunks = (nrows + ROWS - 1) / ROWS;
    for (int chunk = blockIdx.x; chunk < nchunks; chunk += gridDim.x) {
        const int r0 = chunk * ROWS;
        const int nr = min(ROWS, nrows - r0);
        __syncthreads();
        for (int i = tid; i < nr * 128; i += 256) {
            int r = i >> 7, k = i & 127;
            Xs[r][k] = X[(size_t)(r0 + r) * 128 + k];
        }
        __syncthreads();
        float acc[RPT];
#pragma unroll
        for (int i = 0; i < RPT; ++i) acc[i] = 0.f;
#pragma unroll 4
        for (int k = 0; k < 128; ++k) {
            float w = Ws[k * DOUT + col];
#pragma unroll
            for (int i = 0; i < RPT; ++i)
                acc[i] += Xs[rb + i * RPI][k] * w;
        }
#pragma unroll
        for (int i = 0; i < RPT; ++i) {
            int r = rb + i * RPI;
            if (r < nr)
                Y[(size_t)(r0 + r) * DOUT + col] = acc[i] * dinv[r0 + r];
        }
    }
}

// ---------------- CSR gather: out[v] = relu(dinv[v] * sum_e XW[srcs[e]] + b) ----------------
// One wave per destination node. Lanes: g = feature float4 group, sub = parallel edge slot.

template <int D>
__launch_bounds__(256)
__global__ void gather_kernel(const float4* __restrict__ XW, const int* __restrict__ off,
                              const int* __restrict__ srcs, const float* __restrict__ dinv,
                              const float* __restrict__ bias, float4* __restrict__ out, int nN) {
    constexpr int G   = D / 4;    // float4 groups per row (32 or 16)
    constexpr int EPW = 64 / G;   // edges handled in parallel per wave (2 or 4)
    const int lane = threadIdx.x & 63;
    const int g    = lane % G;
    const int sub  = lane / G;
    const int wid  = (blockIdx.x * blockDim.x + threadIdx.x) >> 6;
    const int nw   = (gridDim.x * blockDim.x) >> 6;

    for (int v = wid; v < nN; v += nw) {
        const int s0 = off[v], s1 = off[v + 1];
        float4 acc = make_float4(0.f, 0.f, 0.f, 0.f);
        for (int i = s0 + sub; i < s1; i += EPW) {
            float4 x = XW[(size_t)srcs[i] * G + g];
            acc.x += x.x; acc.y += x.y; acc.z += x.z; acc.w += x.w;
        }
#pragma unroll
        for (int d = 32; d >= G; d >>= 1) {
            acc.x += __shfl_down(acc.x, d);
            acc.y += __shfl_down(acc.y, d);
            acc.z += __shfl_down(acc.z, d);
            acc.w += __shfl_down(acc.w, d);
        }
        if (sub == 0) {
            float dv = dinv[v];
            float4 b = ((const float4*)bias)[g];
            float4 r;
            r.x = fmaxf(dv * acc.x + b.x, 0.f);
            r.y = fmaxf(dv * acc.y + b.y, 0.f);
            r.z = fmaxf(dv * acc.z + b.z, 0.f);
            r.w = fmaxf(dv * acc.w + b.w, 0.f);
            out[(size_t)v * G + g] = r;
        }
    }
}

extern "C" void kernel_launch(void* const* d_in, const int* in_sizes, int n_in,
                              void* d_out, int out_size, void* d_ws, size_t ws_size,
                              hipStream_t stream) {
    const float* feats = (const float*)d_in[0];
    const int*   ei    = (const int*)d_in[1];
    const float* W1    = (const float*)d_in[2];
    const float* b1    = (const float*)d_in[3];
    const float* W2    = (const float*)d_in[4];
    const float* b2    = (const float*)d_in[5];
    const float* W3    = (const float*)d_in[6];
    const float* b3    = (const float*)d_in[7];

    const int N = in_sizes[0] / 128;
    const int E = in_sizes[1] / 2;
    const int* row = ei;       // source
    const int* col = ei + E;   // destination

    // workspace layout
    char* p = (char*)d_ws;
    int*   deg_i  = (int*)p;    p += ALIGNUP((size_t)N * 4);
    int*   off    = (int*)p;    p += ALIGNUP((size_t)(N + 1) * 4);
    int*   cursor = (int*)p;    p += ALIGNUP((size_t)N * 4);
    int*   parts  = (int*)p;    p += ALIGNUP(1024 * 4);
    float* dinv   = (float*)p;  p += ALIGNUP((size_t)N * 4);
    int*   srcs   = (int*)p;    p += ALIGNUP((size_t)E * 4);
    float* bufA   = (float*)p;  p += ALIGNUP((size_t)N * 128 * 4);
    float* bufB   = (float*)p;

    const int NBLK = (N + 255) / 256;   // 391 for N=100k (fits scan2's 1024)

    // ---- CSR build ----
    hipMemsetAsync(deg_i, 0, (size_t)N * sizeof(int), stream);
    deg_kernel<<<2048, THREADS, 0, stream>>>(col, deg_i, E);
    dinv_kernel<<<NBLK, THREADS, 0, stream>>>(deg_i, dinv, N);
    scan1_kernel<<<NBLK, 256, 0, stream>>>(deg_i, off, parts, N);
    scan2_kernel<<<1, 1024, 0, stream>>>(parts, NBLK);
    scan3_kernel<<<NBLK, 256, 0, stream>>>(off, cursor, parts, N, E);
    fill_kernel<<<2048, THREADS, 0, stream>>>(row, col, cursor, srcs, E);

    const int GB = (N + 3) / 4;  // 4 waves/block -> 4 nodes per block-iter

    // ---- layer 1 ----
    gemm_kernel<128, 8><<<1024, 256, 0, stream>>>(feats, W1, dinv, bufA, N);
    gather_kernel<128><<<GB, 256, 0, stream>>>((const float4*)bufA, off, srcs, dinv, b1,
                                               (float4*)bufB, N);
    // ---- layer 2 ----
    gemm_kernel<128, 8><<<1024, 256, 0, stream>>>(bufB, W2, dinv, bufA, N);
    gather_kernel<128><<<GB, 256, 0, stream>>>((const float4*)bufA, off, srcs, dinv, b2,
                                               (float4*)bufB, N);
    // ---- layer 3 ----
    gemm_kernel<64, 8><<<1024, 256, 0, stream>>>(bufB, W3, dinv, bufA, N);
    gather_kernel<64><<<GB, 256, 0, stream>>>((const float4*)bufA, off, srcs, dinv, b3,
                                              (float4*)d_out, N);
}

// Round 3
// 666.388 us; speedup vs baseline: 10.8915x; 1.3169x over previous
//
#include <hip/hip_runtime.h>

#define THREADS 256
#define ALIGNUP(x) (((x) + 255) & ~(size_t)255)

// ---------------- degree histogram (int) ----------------

__global__ void deg_kernel(const int* __restrict__ col, int* __restrict__ deg, int nE) {
    int stride = gridDim.x * blockDim.x;
    for (int e = blockIdx.x * blockDim.x + threadIdx.x; e < nE; e += stride)
        atomicAdd(&deg[col[e]], 1);
}

__global__ void dinv_kernel(const int* __restrict__ deg, float* __restrict__ dinv, int n) {
    int i = blockIdx.x * blockDim.x + threadIdx.x;
    if (i < n) {
        float d = (float)deg[i];
        dinv[i] = d > 0.f ? rsqrtf(fmaxf(d, 1.f)) : 0.f;
    }
}

// ---------------- exclusive scan over deg -> off (3-phase) ----------------

__global__ void scan1_kernel(const int* __restrict__ deg, int* __restrict__ off,
                             int* __restrict__ partials, int n) {
    __shared__ int s[256];
    int tid = threadIdx.x;
    int gid = blockIdx.x * 256 + tid;
    int v = gid < n ? deg[gid] : 0;
    s[tid] = v;
    __syncthreads();
    for (int o = 1; o < 256; o <<= 1) {
        int t = (tid >= o) ? s[tid - o] : 0;
        __syncthreads();
        s[tid] += t;
        __syncthreads();
    }
    if (gid < n) off[gid] = s[tid] - v;          // exclusive within block
    if (tid == 255) partials[blockIdx.x] = s[255];
}

__global__ void scan2_kernel(int* __restrict__ partials, int nblk) {
    __shared__ int s[1024];
    int tid = threadIdx.x;
    int v = tid < nblk ? partials[tid] : 0;
    s[tid] = v;
    __syncthreads();
    for (int o = 1; o < 1024; o <<= 1) {
        int t = (tid >= o) ? s[tid - o] : 0;
        __syncthreads();
        s[tid] += t;
        __syncthreads();
    }
    if (tid < nblk) partials[tid] = s[tid] - v;  // exclusive block bases
}

__global__ void scan3_kernel(int* __restrict__ off, int* __restrict__ cursor,
                             const int* __restrict__ partials, int n, int nE) {
    int gid = blockIdx.x * 256 + threadIdx.x;
    if (gid < n) {
        int o = off[gid] + partials[blockIdx.x];
        off[gid] = o;
        cursor[gid] = o;
    }
    if (gid == 0) off[n] = nE;
}

// ---------------- fill CSR: srcs sorted by destination ----------------

__global__ void fill_kernel(const int* __restrict__ row, const int* __restrict__ col,
                            int* __restrict__ cursor, int* __restrict__ srcs, int nE) {
    int stride = gridDim.x * blockDim.x;
    for (int e = blockIdx.x * blockDim.x + threadIdx.x; e < nE; e += stride) {
        int pos = atomicAdd(&cursor[col[e]], 1);
        srcs[pos] = row[e];
    }
}

// ---------------- register-tiled GEMM: Y[r] = dinv[r] * (X[r,128] @ W[128,DOUT]) --------
// BM=128 rows/block, BK=32 k-chunks. Thread (tx,ty) computes TM=4 rows x TN=8 cols.
// Per k: 4 scalar a-reads (rows ty*4+i, stride 33 dwords -> banks {0,4,8,12} in-wave,
// conflict-free) + 2 float4 b-reads (contiguous). 32 FMAs per k -> FMA-bound.

template <int DOUT, int NT>
__launch_bounds__(NT)
__global__ void gemm_kernel(const float* __restrict__ X, const float* __restrict__ W,
                            const float* __restrict__ dinv, float* __restrict__ Y, int nrows) {
    constexpr int BM = 128, BK = 32, TM = 4, TN = 8;
    constexpr int NTX = DOUT / TN;           // col groups
    static_assert(NT / NTX * TM == BM, "thread map must cover BM rows");
    __shared__ float Ws[BK][DOUT];
    __shared__ float Xs[BM][BK + 1];

    const int tid = threadIdx.x;
    const int tx = tid % NTX;
    const int ty = tid / NTX;
    const int r0 = blockIdx.x * BM;

    float acc[TM][TN];
#pragma unroll
    for (int i = 0; i < TM; ++i)
#pragma unroll
        for (int j = 0; j < TN; ++j) acc[i][j] = 0.f;

    for (int k0 = 0; k0 < 128; k0 += BK) {
        __syncthreads();   // previous chunk's readers done
        // stage W chunk [BK][DOUT] via float4
        constexpr int WF4 = BK * DOUT / 4;
        for (int idx = tid; idx < WF4; idx += NT) {
            int r = idx / (DOUT / 4), c = idx % (DOUT / 4);
            float4 w = ((const float4*)W)[(size_t)(k0 + r) * (DOUT / 4) + c];
            *(float4*)&Ws[r][c * 4] = w;
        }
        // stage X chunk [BM][BK]
        constexpr int XF4 = BM * BK / 4;
        for (int idx = tid; idx < XF4; idx += NT) {
            int r = idx / (BK / 4), q = idx % (BK / 4);
            int gr = min(r0 + r, nrows - 1);
            float4 x = ((const float4*)X)[(size_t)gr * 32 + k0 / 4 + q];
            Xs[r][q * 4 + 0] = x.x;
            Xs[r][q * 4 + 1] = x.y;
            Xs[r][q * 4 + 2] = x.z;
            Xs[r][q * 4 + 3] = x.w;
        }
        __syncthreads();

#pragma unroll 8
        for (int kk = 0; kk < BK; ++kk) {
            float a[TM];
#pragma unroll
            for (int i = 0; i < TM; ++i) a[i] = Xs[ty * TM + i][kk];
            float4 b0 = *(const float4*)&Ws[kk][tx * TN];
            float4 b1 = *(const float4*)&Ws[kk][tx * TN + 4];
            float b[TN] = {b0.x, b0.y, b0.z, b0.w, b1.x, b1.y, b1.z, b1.w};
#pragma unroll
            for (int i = 0; i < TM; ++i)
#pragma unroll
                for (int j = 0; j < TN; ++j)
                    acc[i][j] += a[i] * b[j];
        }
    }

#pragma unroll
    for (int i = 0; i < TM; ++i) {
        int r = r0 + ty * TM + i;
        if (r < nrows) {
            float dv = dinv[r];
            float4 o0, o1;
            o0.x = acc[i][0] * dv; o0.y = acc[i][1] * dv;
            o0.z = acc[i][2] * dv; o0.w = acc[i][3] * dv;
            o1.x = acc[i][4] * dv; o1.y = acc[i][5] * dv;
            o1.z = acc[i][6] * dv; o1.w = acc[i][7] * dv;
            float4* yp = (float4*)&Y[(size_t)r * DOUT + tx * TN];
            yp[0] = o0;
            yp[1] = o1;
        }
    }
}

// ---------------- CSR gather: out[v] = relu(dinv[v] * sum_e XW[srcs[e]] + b) ----------------
// One wave per destination node. Lanes: g = feature float4 group, sub = parallel edge slot.

template <int D>
__launch_bounds__(256)
__global__ void gather_kernel(const float4* __restrict__ XW, const int* __restrict__ off,
                              const int* __restrict__ srcs, const float* __restrict__ dinv,
                              const float* __restrict__ bias, float4* __restrict__ out, int nN) {
    constexpr int G   = D / 4;    // float4 groups per row (32 or 16)
    constexpr int EPW = 64 / G;   // edges handled in parallel per wave (2 or 4)
    const int lane = threadIdx.x & 63;
    const int g    = lane % G;
    const int sub  = lane / G;
    const int wid  = (blockIdx.x * blockDim.x + threadIdx.x) >> 6;
    const int nw   = (gridDim.x * blockDim.x) >> 6;

    for (int v = wid; v < nN; v += nw) {
        const int s0 = off[v], s1 = off[v + 1];
        float4 acc = make_float4(0.f, 0.f, 0.f, 0.f);
        for (int i = s0 + sub; i < s1; i += EPW) {
            float4 x = XW[(size_t)srcs[i] * G + g];
            acc.x += x.x; acc.y += x.y; acc.z += x.z; acc.w += x.w;
        }
#pragma unroll
        for (int d = 32; d >= G; d >>= 1) {
            acc.x += __shfl_down(acc.x, d);
            acc.y += __shfl_down(acc.y, d);
            acc.z += __shfl_down(acc.z, d);
            acc.w += __shfl_down(acc.w, d);
        }
        if (sub == 0) {
            float dv = dinv[v];
            float4 b = ((const float4*)bias)[g];
            float4 r;
            r.x = fmaxf(dv * acc.x + b.x, 0.f);
            r.y = fmaxf(dv * acc.y + b.y, 0.f);
            r.z = fmaxf(dv * acc.z + b.z, 0.f);
            r.w = fmaxf(dv * acc.w + b.w, 0.f);
            out[(size_t)v * G + g] = r;
        }
    }
}

extern "C" void kernel_launch(void* const* d_in, const int* in_sizes, int n_in,
                              void* d_out, int out_size, void* d_ws, size_t ws_size,
                              hipStream_t stream) {
    const float* feats = (const float*)d_in[0];
    const int*   ei    = (const int*)d_in[1];
    const float* W1    = (const float*)d_in[2];
    const float* b1    = (const float*)d_in[3];
    const float* W2    = (const float*)d_in[4];
    const float* b2    = (const float*)d_in[5];
    const float* W3    = (const float*)d_in[6];
    const float* b3    = (const float*)d_in[7];

    const int N = in_sizes[0] / 128;
    const int E = in_sizes[1] / 2;
    const int* row = ei;       // source
    const int* col = ei + E;   // destination

    // workspace layout
    char* p = (char*)d_ws;
    int*   deg_i  = (int*)p;    p += ALIGNUP((size_t)N * 4);
    int*   off    = (int*)p;    p += ALIGNUP((size_t)(N + 1) * 4);
    int*   cursor = (int*)p;    p += ALIGNUP((size_t)N * 4);
    int*   parts  = (int*)p;    p += ALIGNUP(1024 * 4);
    float* dinv   = (float*)p;  p += ALIGNUP((size_t)N * 4);
    int*   srcs   = (int*)p;    p += ALIGNUP((size_t)E * 4);
    float* bufA   = (float*)p;  p += ALIGNUP((size_t)N * 128 * 4);
    float* bufB   = (float*)p;

    const int NBLK  = (N + 255) / 256;   // 391 for N=100k (fits scan2's 1024)
    const int GBLK  = (N + 127) / 128;   // gemm blocks (782)

    // ---- CSR build ----
    hipMemsetAsync(deg_i, 0, (size_t)N * sizeof(int), stream);
    deg_kernel<<<2048, THREADS, 0, stream>>>(col, deg_i, E);
    dinv_kernel<<<NBLK, THREADS, 0, stream>>>(deg_i, dinv, N);
    scan1_kernel<<<NBLK, 256, 0, stream>>>(deg_i, off, parts, N);
    scan2_kernel<<<1, 1024, 0, stream>>>(parts, NBLK);
    scan3_kernel<<<NBLK, 256, 0, stream>>>(off, cursor, parts, N, E);
    fill_kernel<<<2048, THREADS, 0, stream>>>(row, col, cursor, srcs, E);

    const int GB = (N + 3) / 4;  // gather: 4 waves/block -> 4 nodes per block-iter

    // ---- layer 1 ----
    gemm_kernel<128, 512><<<GBLK, 512, 0, stream>>>(feats, W1, dinv, bufA, N);
    gather_kernel<128><<<GB, 256, 0, stream>>>((const float4*)bufA, off, srcs, dinv, b1,
                                               (float4*)bufB, N);
    // ---- layer 2 ----
    gemm_kernel<128, 512><<<GBLK, 512, 0, stream>>>(bufB, W2, dinv, bufA, N);
    gather_kernel<128><<<GB, 256, 0, stream>>>((const float4*)bufA, off, srcs, dinv, b2,
                                               (float4*)bufB, N);
    // ---- layer 3 ----
    gemm_kernel<64, 256><<<GBLK, 256, 0, stream>>>(bufB, W3, dinv, bufA, N);
    gather_kernel<64><<<GB, 256, 0, stream>>>((const float4*)bufA, off, srcs, dinv, b3,
                                              (float4*)d_out, N);
}

// Round 4
// 515.854 us; speedup vs baseline: 14.0698x; 1.2918x over previous
//
#include <hip/hip_runtime.h>

#define ALIGNUP(x) (((x) + 255) & ~(size_t)255)
#define ABLK 256          // blocks for hist/scatter passes
#define BSHIFT 9          // 512 dst nodes per bucket; requires N <= 131072

// ---------------- CSR build: two-level counting sort, LDS atomics only ----------------

__global__ void bucket_hist_kernel(const int* __restrict__ col, unsigned* __restrict__ gHist,
                                   int nE, int chunk) {
    __shared__ unsigned hist[256];
    const int tid = threadIdx.x, blk = blockIdx.x;
    hist[tid] = 0;
    __syncthreads();
    const int e0 = blk * chunk, e1 = min(nE, e0 + chunk);
    for (int e = e0 + tid; e < e1; e += 256)
        atomicAdd(&hist[((unsigned)col[e]) >> BSHIFT], 1u);
    __syncthreads();
    gHist[tid * ABLK + blk] = hist[tid];   // bucket-major
}

// exclusive scan over all 256*ABLK entries, single block of 1024 threads, 64 elems/thread
__global__ void bucket_scan_kernel(unsigned* __restrict__ g) {
    __shared__ unsigned ps[1024];
    const int tid = threadIdx.x;
    const int base = tid * 64;
    unsigned sum = 0;
    for (int k = 0; k < 64; ++k) sum += g[base + k];
    ps[tid] = sum;
    __syncthreads();
    for (int o = 1; o < 1024; o <<= 1) {
        unsigned t = tid >= o ? ps[tid - o] : 0u;
        __syncthreads();
        ps[tid] += t;
        __syncthreads();
    }
    unsigned run = ps[tid] - sum;   // exclusive base for this thread's span
    for (int k = 0; k < 64; ++k) {
        unsigned v = g[base + k];
        g[base + k] = run;
        run += v;
    }
}

__global__ void bucket_scatter_kernel(const int* __restrict__ row, const int* __restrict__ col,
                                      const unsigned* __restrict__ gScan,
                                      unsigned* __restrict__ pairs, int nE, int chunk) {
    __shared__ unsigned basec[256];
    const int tid = threadIdx.x, blk = blockIdx.x;
    basec[tid] = gScan[tid * ABLK + blk];
    __syncthreads();
    const int e0 = blk * chunk, e1 = min(nE, e0 + chunk);
    for (int e = e0 + tid; e < e1; e += 256) {
        unsigned d = (unsigned)col[e];
        unsigned pos = atomicAdd(&basec[d >> BSHIFT], 1u);
        pairs[pos] = (((unsigned)row[e]) << BSHIFT) | (d & 511u);  // src(17b) | dstLow(9b)
    }
}

// one block per bucket: count per-node, scan, emit dinv/off and dst-sorted srcs
__global__ void bucket_sort_kernel(const unsigned* __restrict__ pairs,
                                   const unsigned* __restrict__ gScan,
                                   int* __restrict__ srcs, int* __restrict__ off,
                                   float* __restrict__ dinv, int nN, int nE) {
    __shared__ unsigned cnt[512], sc[512];
    const int tid = threadIdx.x, b = blockIdx.x;
    const unsigned s = gScan[b * ABLK];
    const unsigned t = (b + 1 < 256) ? gScan[(b + 1) * ABLK] : (unsigned)nE;
    cnt[tid] = 0;
    __syncthreads();
    for (unsigned i = s + tid; i < t; i += 512)
        atomicAdd(&cnt[pairs[i] & 511u], 1u);
    __syncthreads();
    const unsigned v = cnt[tid];
    sc[tid] = v;
    __syncthreads();
    for (int o = 1; o < 512; o <<= 1) {
        unsigned q = tid >= o ? sc[tid - o] : 0u;
        __syncthreads();
        sc[tid] += q;
        __syncthreads();
    }
    const unsigned excl = sc[tid] - v;
    const int node = b * 512 + tid;
    if (node < nN) {
        dinv[node] = v > 0 ? rsqrtf((float)v) : 0.f;   // v>=1 -> max(v,1)==v
        off[node] = (int)(s + excl);
    }
    if (b == 0 && tid == 0) off[nN] = nE;
    sc[tid] = excl;          // reuse as cursor (own-slot write after final scan sync)
    __syncthreads();
    for (unsigned i = s + tid; i < t; i += 512) {
        unsigned p = pairs[i];
        unsigned pos = s + atomicAdd(&sc[p & 511u], 1u);
        srcs[pos] = (int)(p >> BSHIFT);
    }
}

// ---------------- register-tiled GEMM: Y[r] = dinv[r] * (X[r,128] @ W[128,DOUT]) --------

template <int DOUT, int NT>
__launch_bounds__(NT)
__global__ void gemm_kernel(const float* __restrict__ X, const float* __restrict__ W,
                            const float* __restrict__ dinv, float* __restrict__ Y, int nrows) {
    constexpr int BM = 128, BK = 32, TM = 4, TN = 8;
    constexpr int NTX = DOUT / TN;           // col groups
    static_assert(NT / NTX * TM == BM, "thread map must cover BM rows");
    __shared__ float Ws[BK][DOUT];
    __shared__ float Xs[BM][BK + 1];

    const int tid = threadIdx.x;
    const int tx = tid % NTX;
    const int ty = tid / NTX;
    const int r0 = blockIdx.x * BM;

    float acc[TM][TN];
#pragma unroll
    for (int i = 0; i < TM; ++i)
#pragma unroll
        for (int j = 0; j < TN; ++j) acc[i][j] = 0.f;

    for (int k0 = 0; k0 < 128; k0 += BK) {
        __syncthreads();
        constexpr int WF4 = BK * DOUT / 4;
        for (int idx = tid; idx < WF4; idx += NT) {
            int r = idx / (DOUT / 4), c = idx % (DOUT / 4);
            float4 w = ((const float4*)W)[(size_t)(k0 + r) * (DOUT / 4) + c];
            *(float4*)&Ws[r][c * 4] = w;
        }
        constexpr int XF4 = BM * BK / 4;
        for (int idx = tid; idx < XF4; idx += NT) {
            int r = idx / (BK / 4), q = idx % (BK / 4);
            int gr = min(r0 + r, nrows - 1);
            float4 x = ((const float4*)X)[(size_t)gr * 32 + k0 / 4 + q];
            Xs[r][q * 4 + 0] = x.x;
            Xs[r][q * 4 + 1] = x.y;
            Xs[r][q * 4 + 2] = x.z;
            Xs[r][q * 4 + 3] = x.w;
        }
        __syncthreads();

#pragma unroll 8
        for (int kk = 0; kk < BK; ++kk) {
            float a[TM];
#pragma unroll
            for (int i = 0; i < TM; ++i) a[i] = Xs[ty * TM + i][kk];
            float4 b0 = *(const float4*)&Ws[kk][tx * TN];
            float4 b1 = *(const float4*)&Ws[kk][tx * TN + 4];
            float b[TN] = {b0.x, b0.y, b0.z, b0.w, b1.x, b1.y, b1.z, b1.w};
#pragma unroll
            for (int i = 0; i < TM; ++i)
#pragma unroll
                for (int j = 0; j < TN; ++j)
                    acc[i][j] += a[i] * b[j];
        }
    }

#pragma unroll
    for (int i = 0; i < TM; ++i) {
        int r = r0 + ty * TM + i;
        if (r < nrows) {
            float dv = dinv[r];
            float4 o0, o1;
            o0.x = acc[i][0] * dv; o0.y = acc[i][1] * dv;
            o0.z = acc[i][2] * dv; o0.w = acc[i][3] * dv;
            o1.x = acc[i][4] * dv; o1.y = acc[i][5] * dv;
            o1.z = acc[i][6] * dv; o1.w = acc[i][7] * dv;
            float4* yp = (float4*)&Y[(size_t)r * DOUT + tx * TN];
            yp[0] = o0;
            yp[1] = o1;
        }
    }
}

// ---------------- CSR gather: out[v] = relu(dinv[v] * sum_e XW[srcs[e]] + b) ----------------

template <int D>
__launch_bounds__(256)
__global__ void gather_kernel(const float4* __restrict__ XW, const int* __restrict__ off,
                              const int* __restrict__ srcs, const float* __restrict__ dinv,
                              const float* __restrict__ bias, float4* __restrict__ out, int nN) {
    constexpr int G   = D / 4;    // float4 groups per row (32 or 16)
    constexpr int EPW = 64 / G;   // edges handled in parallel per wave (2 or 4)
    const int lane = threadIdx.x & 63;
    const int g    = lane % G;
    const int sub  = lane / G;
    const int wid  = (blockIdx.x * blockDim.x + threadIdx.x) >> 6;
    const int nw   = (gridDim.x * blockDim.x) >> 6;

    for (int v = wid; v < nN; v += nw) {
        const int s0 = off[v], s1 = off[v + 1];
        float4 acc = make_float4(0.f, 0.f, 0.f, 0.f);
        for (int i = s0 + sub; i < s1; i += EPW) {
            float4 x = XW[(size_t)srcs[i] * G + g];
            acc.x += x.x; acc.y += x.y; acc.z += x.z; acc.w += x.w;
        }
#pragma unroll
        for (int d = 32; d >= G; d >>= 1) {
            acc.x += __shfl_down(acc.x, d);
            acc.y += __shfl_down(acc.y, d);
            acc.z += __shfl_down(acc.z, d);
            acc.w += __shfl_down(acc.w, d);
        }
        if (sub == 0) {
            float dv = dinv[v];
            float4 b = ((const float4*)bias)[g];
            float4 r;
            r.x = fmaxf(dv * acc.x + b.x, 0.f);
            r.y = fmaxf(dv * acc.y + b.y, 0.f);
            r.z = fmaxf(dv * acc.z + b.z, 0.f);
            r.w = fmaxf(dv * acc.w + b.w, 0.f);
            out[(size_t)v * G + g] = r;
        }
    }
}

extern "C" void kernel_launch(void* const* d_in, const int* in_sizes, int n_in,
                              void* d_out, int out_size, void* d_ws, size_t ws_size,
                              hipStream_t stream) {
    const float* feats = (const float*)d_in[0];
    const int*   ei    = (const int*)d_in[1];
    const float* W1    = (const float*)d_in[2];
    const float* b1    = (const float*)d_in[3];
    const float* W2    = (const float*)d_in[4];
    const float* b2    = (const float*)d_in[5];
    const float* W3    = (const float*)d_in[6];
    const float* b3    = (const float*)d_in[7];

    const int N = in_sizes[0] / 128;
    const int E = in_sizes[1] / 2;
    const int* row = ei;       // source
    const int* col = ei + E;   // destination

    // workspace layout
    char* p = (char*)d_ws;
    unsigned* gHist = (unsigned*)p; p += ALIGNUP((size_t)256 * ABLK * 4);
    float* dinv = (float*)p;        p += ALIGNUP((size_t)N * 4);
    int*   off  = (int*)p;          p += ALIGNUP((size_t)(N + 1) * 4);
    int*   srcs = (int*)p;          p += ALIGNUP((size_t)E * 4);
    float* bufA = (float*)p;        p += ALIGNUP((size_t)N * 128 * 4);
    float* bufB = (float*)p;
    unsigned* pairs = (unsigned*)bufB;   // alias: pairs dead before gather1 writes bufB

    // ---- CSR build (no global atomics) ----
    const int chunk = (E + ABLK - 1) / ABLK;
    const int NB    = (N + 511) >> BSHIFT;          // buckets actually populated (<=256)
    bucket_hist_kernel<<<ABLK, 256, 0, stream>>>(col, gHist, E, chunk);
    bucket_scan_kernel<<<1, 1024, 0, stream>>>(gHist);
    bucket_scatter_kernel<<<ABLK, 256, 0, stream>>>(row, col, gHist, pairs, E, chunk);
    bucket_sort_kernel<<<NB, 512, 0, stream>>>(pairs, gHist, srcs, off, dinv, N, E);

    const int GBLK = (N + 127) / 128;   // gemm blocks
    const int GB   = (N + 3) / 4;       // gather: 4 waves/block

    // ---- layer 1 ----
    gemm_kernel<128, 512><<<GBLK, 512, 0, stream>>>(feats, W1, dinv, bufA, N);
    gather_kernel<128><<<GB, 256, 0, stream>>>((const float4*)bufA, off, srcs, dinv, b1,
                                               (float4*)bufB, N);
    // ---- layer 2 ----
    gemm_kernel<128, 512><<<GBLK, 512, 0, stream>>>(bufB, W2, dinv, bufA, N);
    gather_kernel<128><<<GB, 256, 0, stream>>>((const float4*)bufA, off, srcs, dinv, b2,
                                               (float4*)bufB, N);
    // ---- layer 3 ----
    gemm_kernel<64, 256><<<GBLK, 256, 0, stream>>>(bufB, W3, dinv, bufA, N);
    gather_kernel<64><<<GB, 256, 0, stream>>>((const float4*)bufA, off, srcs, dinv, b3,
                                              (float4*)d_out, N);
}

// Round 5
// 396.529 us; speedup vs baseline: 18.3037x; 1.3009x over previous
//
#include <hip/hip_runtime.h>
#include <hip/hip_fp16.h>

#define ALIGNUP(x) (((x) + 255) & ~(size_t)255)
#define ABLK 256          // blocks for hist/scatter passes
#define BSHIFT 9          // 512 dst nodes per bucket; requires N <= 131072

// ---------------- CSR build: two-level counting sort, LDS atomics only ----------------

__global__ void bucket_hist_kernel(const int* __restrict__ col, unsigned* __restrict__ gHist,
                                   int nE, int chunk) {
    __shared__ unsigned hist[256];
    const int tid = threadIdx.x, blk = blockIdx.x;
    hist[tid] = 0;
    __syncthreads();
    const int e0 = blk * chunk, e1 = min(nE, e0 + chunk);
    for (int e = e0 + tid; e < e1; e += 256)
        atomicAdd(&hist[((unsigned)col[e]) >> BSHIFT], 1u);
    __syncthreads();
    gHist[tid * ABLK + blk] = hist[tid];   // bucket-major
}

// exclusive scan over all 256*ABLK entries, single block of 1024 threads, 64 elems/thread
__global__ void bucket_scan_kernel(unsigned* __restrict__ g) {
    __shared__ unsigned ps[1024];
    const int tid = threadIdx.x;
    const int base = tid * 64;
    unsigned sum = 0;
    for (int k = 0; k < 64; ++k) sum += g[base + k];
    ps[tid] = sum;
    __syncthreads();
    for (int o = 1; o < 1024; o <<= 1) {
        unsigned t = tid >= o ? ps[tid - o] : 0u;
        __syncthreads();
        ps[tid] += t;
        __syncthreads();
    }
    unsigned run = ps[tid] - sum;   // exclusive base for this thread's span
    for (int k = 0; k < 64; ++k) {
        unsigned v = g[base + k];
        g[base + k] = run;
        run += v;
    }
}

__global__ void bucket_scatter_kernel(const int* __restrict__ row, const int* __restrict__ col,
                                      const unsigned* __restrict__ gScan,
                                      unsigned* __restrict__ pairs, int nE, int chunk) {
    __shared__ unsigned basec[256];
    const int tid = threadIdx.x, blk = blockIdx.x;
    basec[tid] = gScan[tid * ABLK + blk];
    __syncthreads();
    const int e0 = blk * chunk, e1 = min(nE, e0 + chunk);
    for (int e = e0 + tid; e < e1; e += 256) {
        unsigned d = (unsigned)col[e];
        unsigned pos = atomicAdd(&basec[d >> BSHIFT], 1u);
        pairs[pos] = (((unsigned)row[e]) << BSHIFT) | (d & 511u);  // src(17b) | dstLow(9b)
    }
}

// one block per bucket: count per-node, scan, emit dinv/off and dst-sorted srcs
__global__ void bucket_sort_kernel(const unsigned* __restrict__ pairs,
                                   const unsigned* __restrict__ gScan,
                                   int* __restrict__ srcs, int* __restrict__ off,
                                   float* __restrict__ dinv, int nN, int nE) {
    __shared__ unsigned cnt[512], sc[512];
    const int tid = threadIdx.x, b = blockIdx.x;
    const unsigned s = gScan[b * ABLK];
    const unsigned t = (b + 1 < 256) ? gScan[(b + 1) * ABLK] : (unsigned)nE;
    cnt[tid] = 0;
    __syncthreads();
    for (unsigned i = s + tid; i < t; i += 512)
        atomicAdd(&cnt[pairs[i] & 511u], 1u);
    __syncthreads();
    const unsigned v = cnt[tid];
    sc[tid] = v;
    __syncthreads();
    for (int o = 1; o < 512; o <<= 1) {
        unsigned q = tid >= o ? sc[tid - o] : 0u;
        __syncthreads();
        sc[tid] += q;
        __syncthreads();
    }
    const unsigned excl = sc[tid] - v;
    const int node = b * 512 + tid;
    if (node < nN) {
        dinv[node] = v > 0 ? rsqrtf((float)v) : 0.f;
        off[node] = (int)(s + excl);
    }
    if (b == 0 && tid == 0) off[nN] = nE;
    sc[tid] = excl;          // reuse as cursor
    __syncthreads();
    for (unsigned i = s + tid; i < t; i += 512) {
        unsigned p = pairs[i];
        unsigned pos = s + atomicAdd(&sc[p & 511u], 1u);
        srcs[pos] = (int)(p >> BSHIFT);
    }
}

// -------- register-tiled GEMM: Yh[r] = half(dinv[r] * (X[r,128] @ W[128,DOUT])) --------

template <int DOUT, int NT>
__launch_bounds__(NT)
__global__ void gemm_kernel(const float* __restrict__ X, const float* __restrict__ W,
                            const float* __restrict__ dinv, __half* __restrict__ Y, int nrows) {
    constexpr int BM = 128, BK = 32, TM = 4, TN = 8;
    constexpr int NTX = DOUT / TN;
    static_assert(NT / NTX * TM == BM, "thread map must cover BM rows");
    __shared__ float Ws[BK][DOUT];
    __shared__ float Xs[BM][BK + 1];

    const int tid = threadIdx.x;
    const int tx = tid % NTX;
    const int ty = tid / NTX;
    const int r0 = blockIdx.x * BM;

    float acc[TM][TN];
#pragma unroll
    for (int i = 0; i < TM; ++i)
#pragma unroll
        for (int j = 0; j < TN; ++j) acc[i][j] = 0.f;

    for (int k0 = 0; k0 < 128; k0 += BK) {
        __syncthreads();
        constexpr int WF4 = BK * DOUT / 4;
        for (int idx = tid; idx < WF4; idx += NT) {
            int r = idx / (DOUT / 4), c = idx % (DOUT / 4);
            float4 w = ((const float4*)W)[(size_t)(k0 + r) * (DOUT / 4) + c];
            *(float4*)&Ws[r][c * 4] = w;
        }
        constexpr int XF4 = BM * BK / 4;
        for (int idx = tid; idx < XF4; idx += NT) {
            int r = idx / (BK / 4), q = idx % (BK / 4);
            int gr = min(r0 + r, nrows - 1);
            float4 x = ((const float4*)X)[(size_t)gr * 32 + k0 / 4 + q];
            Xs[r][q * 4 + 0] = x.x;
            Xs[r][q * 4 + 1] = x.y;
            Xs[r][q * 4 + 2] = x.z;
            Xs[r][q * 4 + 3] = x.w;
        }
        __syncthreads();

#pragma unroll 8
        for (int kk = 0; kk < BK; ++kk) {
            float a[TM];
#pragma unroll
            for (int i = 0; i < TM; ++i) a[i] = Xs[ty * TM + i][kk];
            float4 b0 = *(const float4*)&Ws[kk][tx * TN];
            float4 b1 = *(const float4*)&Ws[kk][tx * TN + 4];
            float b[TN] = {b0.x, b0.y, b0.z, b0.w, b1.x, b1.y, b1.z, b1.w};
#pragma unroll
            for (int i = 0; i < TM; ++i)
#pragma unroll
                for (int j = 0; j < TN; ++j)
                    acc[i][j] += a[i] * b[j];
        }
    }

#pragma unroll
    for (int i = 0; i < TM; ++i) {
        int r = r0 + ty * TM + i;
        if (r < nrows) {
            float dv = dinv[r];
            union { __half h[8]; uint4 u; } o;
#pragma unroll
            for (int j = 0; j < TN; ++j) o.h[j] = __float2half(acc[i][j] * dv);
            *(uint4*)&Y[(size_t)r * DOUT + tx * TN] = o.u;
        }
    }
}

// -------- CSR gather (f16 rows): out[v] = relu(dinv[v] * sum_e XWh[srcs[e]] + b) --------
// One wave per destination node. Lane = sub*G + g: g indexes 16B (8 halves) of the row,
// sub processes EPW edges in parallel. f32 accumulate; f32 epilogue.

template <int D>
__launch_bounds__(256)
__global__ void gather_kernel(const __half* __restrict__ XW, const int* __restrict__ off,
                              const int* __restrict__ srcs, const float* __restrict__ dinv,
                              const float* __restrict__ bias, float* __restrict__ out, int nN) {
    constexpr int G   = D / 8;    // 16B chunks per row (16 for D=128, 8 for D=64)
    constexpr int EPW = 64 / G;   // edges in parallel per wave (4 or 8)
    const int lane = threadIdx.x & 63;
    const int g    = lane % G;
    const int sub  = lane / G;
    const int wid  = (blockIdx.x * blockDim.x + threadIdx.x) >> 6;
    const int nw   = (gridDim.x * blockDim.x) >> 6;

    for (int v = wid; v < nN; v += nw) {
        const int s0 = off[v], s1 = off[v + 1];
        float acc[8];
#pragma unroll
        for (int k = 0; k < 8; ++k) acc[k] = 0.f;
        for (int i = s0 + sub; i < s1; i += EPW) {
            union { uint4 u; __half h[8]; } cv;
            cv.u = ((const uint4*)(XW + (size_t)srcs[i] * D))[g];
#pragma unroll
            for (int k = 0; k < 8; ++k) acc[k] += __half2float(cv.h[k]);
        }
#pragma unroll
        for (int d = 32; d >= G; d >>= 1)
#pragma unroll
            for (int k = 0; k < 8; ++k) acc[k] += __shfl_down(acc[k], d);
        if (sub == 0) {
            float dv = dinv[v];
            float4 b0 = ((const float4*)bias)[g * 2];
            float4 b1 = ((const float4*)bias)[g * 2 + 1];
            float4 o0, o1;
            o0.x = fmaxf(dv * acc[0] + b0.x, 0.f);
            o0.y = fmaxf(dv * acc[1] + b0.y, 0.f);
            o0.z = fmaxf(dv * acc[2] + b0.z, 0.f);
            o0.w = fmaxf(dv * acc[3] + b0.w, 0.f);
            o1.x = fmaxf(dv * acc[4] + b1.x, 0.f);
            o1.y = fmaxf(dv * acc[5] + b1.y, 0.f);
            o1.z = fmaxf(dv * acc[6] + b1.z, 0.f);
            o1.w = fmaxf(dv * acc[7] + b1.w, 0.f);
            float4* op = (float4*)(out + (size_t)v * D + g * 8);
            op[0] = o0;
            op[1] = o1;
        }
    }
}

extern "C" void kernel_launch(void* const* d_in, const int* in_sizes, int n_in,
                              void* d_out, int out_size, void* d_ws, size_t ws_size,
                              hipStream_t stream) {
    const float* feats = (const float*)d_in[0];
    const int*   ei    = (const int*)d_in[1];
    const float* W1    = (const float*)d_in[2];
    const float* b1    = (const float*)d_in[3];
    const float* W2    = (const float*)d_in[4];
    const float* b2    = (const float*)d_in[5];
    const float* W3    = (const float*)d_in[6];
    const float* b3    = (const float*)d_in[7];

    const int N = in_sizes[0] / 128;
    const int E = in_sizes[1] / 2;
    const int* row = ei;       // source
    const int* col = ei + E;   // destination

    // workspace layout
    char* p = (char*)d_ws;
    unsigned* gHist = (unsigned*)p; p += ALIGNUP((size_t)256 * ABLK * 4);
    float*  dinv = (float*)p;       p += ALIGNUP((size_t)N * 4);
    int*    off  = (int*)p;         p += ALIGNUP((size_t)(N + 1) * 4);
    int*    srcs = (int*)p;         p += ALIGNUP((size_t)E * 4);
    __half* bufH = (__half*)p;      p += ALIGNUP((size_t)N * 128 * 2);
    float*  bufA = (float*)p;
    unsigned* pairs = (unsigned*)bufA;  // alias: pairs consumed before gather1 writes bufA

    // ---- CSR build (no global atomics) ----
    const int chunk = (E + ABLK - 1) / ABLK;
    const int NB    = (N + 511) >> BSHIFT;
    bucket_hist_kernel<<<ABLK, 256, 0, stream>>>(col, gHist, E, chunk);
    bucket_scan_kernel<<<1, 1024, 0, stream>>>(gHist);
    bucket_scatter_kernel<<<ABLK, 256, 0, stream>>>(row, col, gHist, pairs, E, chunk);
    bucket_sort_kernel<<<NB, 512, 0, stream>>>(pairs, gHist, srcs, off, dinv, N, E);

    const int GBLK = (N + 127) / 128;   // gemm blocks
    const int GB   = (N + 3) / 4;       // gather: 4 waves/block

    // ---- layer 1: feats @ W1 -> bufH (f16); agg -> bufA (f32) ----
    gemm_kernel<128, 512><<<GBLK, 512, 0, stream>>>(feats, W1, dinv, bufH, N);
    gather_kernel<128><<<GB, 256, 0, stream>>>(bufH, off, srcs, dinv, b1, bufA, N);
    // ---- layer 2: bufA @ W2 -> bufH; agg -> bufA (in place, gather reads only bufH) ----
    gemm_kernel<128, 512><<<GBLK, 512, 0, stream>>>(bufA, W2, dinv, bufH, N);
    gather_kernel<128><<<GB, 256, 0, stream>>>(bufH, off, srcs, dinv, b2, bufA, N);
    // ---- layer 3: bufA @ W3 -> bufH (64-wide); agg -> d_out ----
    gemm_kernel<64, 256><<<GBLK, 256, 0, stream>>>(bufA, W3, dinv, bufH, N);
    gather_kernel<64><<<GB, 256, 0, stream>>>(bufH, off, srcs, dinv, b3, (float*)d_out, N);
}